// Round 16
// baseline (286.235 us; speedup 1.0000x reference)
//
#include <hip/hip_runtime.h>
#include <hip/hip_bf16.h>

typedef __hip_bfloat16 bf16;
typedef __attribute__((ext_vector_type(8))) __bf16 bf16x8;
typedef __attribute__((ext_vector_type(4))) float floatx4;

#define NB 2
#define NL 2048
#define NC 1024
#define NH 16
#define ND 64

__device__ __forceinline__ void async_copy16(void* lds, const void* g) {
  __builtin_amdgcn_global_load_lds(
      (__attribute__((address_space(1))) void*)(const_cast<void*>(g)),
      (__attribute__((address_space(3))) void*)(lds), 16, 0, 0);
}

__device__ __forceinline__ floatx4 mfma16(bf16x8 a, bf16x8 b, floatx4 c) {
  return __builtin_amdgcn_mfma_f32_16x16x32_bf16(a, b, c, 0, 0, 0);
}

// ---------------- prep: gn partial stats (512 blocks) + qkv_w transpose -----
__global__ __launch_bounds__(256) void prep_kernel(
    const float* __restrict__ x, float2* __restrict__ part,
    const float* __restrict__ qkv_w, bf16* __restrict__ wqkvT) {
  __shared__ float t[32][33];
  __shared__ float rs[4], rss[4];
  int tid = threadIdx.x;
  if (blockIdx.x < 512) {
    // ---- GroupNorm partial stats: block = (bg, L/8 slice) ----
    int bg = blockIdx.x >> 3, sl = blockIdx.x & 7;
    int b = bg >> 5, g = bg & 31;
    const float* base = x + (size_t)b * NL * NC + (size_t)(sl * 256) * NC + g * 32;
    float s = 0.f, ss = 0.f;
    for (int vi = tid; vi < 2048; vi += 256) {
      int l = vi >> 3, j = (vi & 7) * 4;
      float4 u = *(const float4*)(base + (size_t)l * NC + j);
      s += u.x + u.y + u.z + u.w;
      ss += u.x * u.x + u.y * u.y + u.z * u.z + u.w * u.w;
    }
    for (int off = 32; off; off >>= 1) {
      s += __shfl_down(s, off);
      ss += __shfl_down(ss, off);
    }
    int wave = tid >> 6, lane = tid & 63;
    if (lane == 0) { rs[wave] = s; rss[wave] = ss; }
    __syncthreads();
    if (tid == 0) {
      part[blockIdx.x] = make_float2(rs[0] + rs[1] + rs[2] + rs[3],
                                     rss[0] + rss[1] + rss[2] + rss[3]);
    }
  } else {
    // ---- transpose fp32 [1024,3072] -> bf16 [3072,1024] ----
    int tb = blockIdx.x - 512;
    int bx = tb % 96, by = tb / 96;
    int tx = tid & 31, ty = tid >> 5;
    int c0 = bx * 32, r0 = by * 32;
#pragma unroll
    for (int j = 0; j < 4; ++j)
      t[ty + j * 8][tx] = qkv_w[(size_t)(r0 + ty + j * 8) * 3072 + c0 + tx];
    __syncthreads();
#pragma unroll
    for (int j = 0; j < 4; ++j)
      wqkvT[(size_t)(c0 + ty + j * 8) * 1024 + r0 + tx] =
          __float2bfloat16(t[tx][ty + j * 8]);
  }
}

// ---------------- GroupNorm apply (folds partial reduction) -----------------
__global__ __launch_bounds__(256) void gn_apply_kernel(
    const float* __restrict__ x, const float2* __restrict__ part,
    const float* __restrict__ scale, const float* __restrict__ bias,
    bf16* __restrict__ xn) {
  size_t idx = (size_t)blockIdx.x * 256 + threadIdx.x;
  size_t e = idx * 8;
  int c = (int)(e & (NC - 1));
  int b = (int)(e >> 21);
  int bg = b * 32 + (c >> 5);
  float s = 0.f, ss = 0.f;
#pragma unroll
  for (int i = 0; i < 8; ++i) {
    float2 p = part[bg * 8 + i];
    s += p.x; ss += p.y;
  }
  float mean = s * (1.f / 65536.f);
  float var = ss * (1.f / 65536.f) - mean * mean;
  float rstd = rsqrtf(var + 1e-6f);
  float4 x0 = *(const float4*)(x + e);
  float4 x1 = *(const float4*)(x + e + 4);
  float4 s0 = *(const float4*)(scale + c);
  float4 s1 = *(const float4*)(scale + c + 4);
  float4 b0 = *(const float4*)(bias + c);
  float4 b1 = *(const float4*)(bias + c + 4);
  float xv[8] = {x0.x, x0.y, x0.z, x0.w, x1.x, x1.y, x1.z, x1.w};
  float sv[8] = {s0.x, s0.y, s0.z, s0.w, s1.x, s1.y, s1.z, s1.w};
  float bv[8] = {b0.x, b0.y, b0.z, b0.w, b1.x, b1.y, b1.z, b1.w};
  bf16 o[8];
#pragma unroll
  for (int k = 0; k < 8; ++k)
    o[k] = __float2bfloat16((xv[k] - mean) * rstd * sv[k] + bv[k]);
  *(uint4*)(xn + e) = *(const uint4*)o;
}

// ---------------- transpose + convert: fp32 [R,C] -> bf16 [C,R] -------------
__global__ void transpose_f32_bf16(const float* __restrict__ in,
                                   bf16* __restrict__ out, int R, int C) {
  __shared__ float t[32][33];
  int c0 = blockIdx.x * 32, r0 = blockIdx.y * 32;
#pragma unroll
  for (int j = 0; j < 4; ++j)
    t[threadIdx.y + j * 8][threadIdx.x] =
        in[(size_t)(r0 + threadIdx.y + j * 8) * C + c0 + threadIdx.x];
  __syncthreads();
#pragma unroll
  for (int j = 0; j < 4; ++j)
    out[(size_t)(c0 + threadIdx.y + j * 8) * R + r0 + threadIdx.x] =
        __float2bfloat16(t[threadIdx.x][threadIdx.y + j * 8]);
}

// ---------------- GEMM: C[M,N] = A[M,K] * Bt[N,K]^T + bias ------------------
// MODE 0: scatter Q*(0.125*log2e), K, Vt (packed uint2 V stores)
// MODE 1: out_f32 = (xres + C) / sqrt(2)
template <int MODE, int NT>
__global__ __launch_bounds__(256) void gemm_kernel(
    const bf16* __restrict__ A, const bf16* __restrict__ Bt,
    const float* __restrict__ biasv, const float* __restrict__ xres,
    bf16* __restrict__ Qo, bf16* __restrict__ Ko, bf16* __restrict__ Vto,
    float* __restrict__ out, int M, int N, int K) {
  constexpr int NFR = NT / 32;
  __shared__ bf16 As[128 * 32];
  __shared__ bf16 Bs[NT * 32];
  int tid = threadIdx.x, wave = tid >> 6, lane = tid & 63;
  int col = lane & 15, quad = lane >> 4;
  int mB = blockIdx.y * 128, nB = blockIdx.x * NT;
  int wm = (wave >> 1) * 64, wn = (wave & 1) * (NT / 2);
  floatx4 acc[4][NFR];
#pragma unroll
  for (int i = 0; i < 4; ++i)
#pragma unroll
    for (int j = 0; j < NFR; ++j) acc[i][j] = (floatx4){0.f, 0.f, 0.f, 0.f};

  int rowOff = wave * 32 + (lane >> 2);
  int rowOffB = (NT == 128) ? rowOff : (wave * 16 + (lane >> 2));
  int kOff = (lane & 3) * 8;

  for (int k0 = 0; k0 < K; k0 += 32) {
    __syncthreads();
    const bf16* ga = A + (size_t)(mB + rowOff) * K + k0 + kOff;
    async_copy16(&As[(wave * 32) * 32], ga);
    async_copy16(&As[(wave * 32 + 16) * 32], ga + (size_t)16 * K);
    const bf16* gb = Bt + (size_t)(nB + rowOffB) * K + k0 + kOff;
    if (NT == 128) {
      async_copy16(&Bs[(wave * 32) * 32], gb);
      async_copy16(&Bs[(wave * 32 + 16) * 32], gb + (size_t)16 * K);
    } else {
      async_copy16(&Bs[(wave * 16) * 32], gb);
    }
    __syncthreads();
    bf16x8 af[4], bfr[NFR];
#pragma unroll
    for (int mi = 0; mi < 4; ++mi)
      af[mi] = *(const bf16x8*)&As[(wm + mi * 16 + col) * 32 + quad * 8];
#pragma unroll
    for (int ni = 0; ni < NFR; ++ni)
      bfr[ni] = *(const bf16x8*)&Bs[(wn + ni * 16 + col) * 32 + quad * 8];
#pragma unroll
    for (int mi = 0; mi < 4; ++mi)
#pragma unroll
      for (int ni = 0; ni < NFR; ++ni)
        acc[mi][ni] = mfma16(af[mi], bfr[ni], acc[mi][ni]);
  }

#pragma unroll
  for (int mi = 0; mi < 4; ++mi)
#pragma unroll
    for (int ni = 0; ni < NFR; ++ni) {
      int row0 = mB + wm + mi * 16 + quad * 4;
      int ncol = nB + wn + ni * 16 + col;
      float vv[4];
#pragma unroll
      for (int r = 0; r < 4; ++r) vv[r] = acc[mi][ni][r] + biasv[ncol];
      if (MODE == 0) {
        int b = row0 >> 11, f0 = row0 & 2047;
        int h = ncol / 192, rr = ncol - h * 192;
        size_t bh = (size_t)(b * NH + h);
        if (rr < 64) {
#pragma unroll
          for (int r = 0; r < 4; ++r)
            Qo[(bh * NL + f0 + r) * 64 + rr] =
                __float2bfloat16(vv[r] * 0.18033688011112042f);  // 0.125*log2e
        } else if (rr < 128) {
#pragma unroll
          for (int r = 0; r < 4; ++r)
            Ko[(bh * NL + f0 + r) * 64 + rr - 64] = __float2bfloat16(vv[r]);
        } else {
          bf16 pk[4];
#pragma unroll
          for (int r = 0; r < 4; ++r) pk[r] = __float2bfloat16(vv[r]);
          *(uint2*)&Vto[(bh * 64 + (rr - 128)) * NL + f0] = *(const uint2*)pk;
        }
      } else {
#pragma unroll
        for (int r = 0; r < 4; ++r) {
          size_t o = (size_t)(row0 + r) * N + ncol;
          out[o] = (xres[o] + vv[r]) * 0.70710678118654752f;
        }
      }
    }
}

// ---------------- Flash attention v10 (62.4us floor) + exp2f ----------------
// 8 waves x 32 Q-rows = 256 rows/block; double-buffered global_load_lds;
// XOR-chunk swizzle; one barrier/iter. Launched twice (bh halves) so the
// other pipeline kernels surface in rocprof's top-5.
__global__ __launch_bounds__(512, 2) void attn_kernel(
    const bf16* __restrict__ Q, const bf16* __restrict__ Kb,
    const bf16* __restrict__ Vt, bf16* __restrict__ hout, int byoff) {
  int qt = blockIdx.x, bh = blockIdx.y + byoff;
  int b = bh >> 4, h = bh & 15;
  int tid = threadIdx.x, wave = tid >> 6, lane = tid & 63;
  int m = lane & 15, quad = lane >> 4;

  __shared__ bf16 Kd[2][4096];
  __shared__ bf16 Vd[2][4096];
  __shared__ bf16 Pp[8][2048];

  bf16* Psw = Pp[wave];

  const bf16* Kg = Kb + (size_t)bh * NL * 64;
  const bf16* Vg = Vt + (size_t)bh * 64 * NL;

  bf16x8 bq[2][2];
  {
    const bf16* Qg = Q + ((size_t)bh * NL + qt * 256 + wave * 32) * 64;
#pragma unroll
    for (int nf = 0; nf < 2; ++nf)
#pragma unroll
      for (int c = 0; c < 2; ++c)
        bq[nf][c] = *(const bf16x8*)&Qg[(size_t)(nf * 16 + m) * 64 + c * 32 + quad * 8];
  }

  float lrow[2] = {0.f, 0.f};
  floatx4 o[2][4];
#pragma unroll
  for (int nf = 0; nf < 2; ++nf)
#pragma unroll
    for (int di = 0; di < 4; ++di) o[nf][di] = (floatx4){0.f, 0.f, 0.f, 0.f};

  int srow = lane >> 3, schunk = lane & 7;

  auto stage = [&](int bufi, int t0) {
    int r0 = wave * 8;
    int r = r0 + srow;
    int cg = schunk ^ (r & 7);
    async_copy16(&Kd[bufi][r0 * 64], Kg + (size_t)(t0 + r) * 64 + cg * 8);
    async_copy16(&Vd[bufi][r0 * 64], Vg + (size_t)r * NL + t0 + cg * 8);
  };

  stage(0, 0);
  __syncthreads();

  int buf = 0;
  for (int t0 = 0; t0 < NL; t0 += 64) {
    if (t0 + 64 < NL) stage(buf ^ 1, t0 + 64);

    const bf16* Kbase = Kd[buf];
    const bf16* Vbase = Vd[buf];

    floatx4 s[2][4];
#pragma unroll
    for (int nf = 0; nf < 2; ++nf)
#pragma unroll
      for (int ti = 0; ti < 4; ++ti) s[nf][ti] = (floatx4){0.f, 0.f, 0.f, 0.f};
#pragma unroll
    for (int ti = 0; ti < 4; ++ti)
#pragma unroll
      for (int c = 0; c < 2; ++c) {
        bf16x8 ak = *(const bf16x8*)
            &Kbase[(ti * 16 + m) * 64 + ((c * 4 + quad) ^ (m & 7)) * 8];
        s[0][ti] = mfma16(ak, bq[0][c], s[0][ti]);
        s[1][ti] = mfma16(ak, bq[1][c], s[1][ti]);
      }

#pragma unroll
    for (int nf = 0; nf < 2; ++nf) {
      float ls = 0.f;
#pragma unroll
      for (int ti = 0; ti < 4; ++ti)
#pragma unroll
        for (int r = 0; r < 4; ++r) {
          float p = exp2f(s[nf][ti][r]);   // Q pre-scaled by 0.125*log2e
          s[nf][ti][r] = p;
          ls += p;
        }
      ls += __shfl_xor(ls, 16);
      ls += __shfl_xor(ls, 32);
      lrow[nf] += ls;
#pragma unroll
      for (int ti = 0; ti < 4; ++ti) {
        bf16 pk[4];
#pragma unroll
        for (int r = 0; r < 4; ++r) pk[r] = __float2bfloat16(s[nf][ti][r]);
        int ct = ti * 2 + (quad >> 1);
        *(uint2*)&Psw[(nf * 16 + m) * 64 + ((ct ^ (m & 7)) * 8) + (quad & 1) * 4] =
            *(const uint2*)pk;
      }
    }

#pragma unroll
    for (int c = 0; c < 2; ++c) {
      bf16x8 bp[2];
#pragma unroll
      for (int nf = 0; nf < 2; ++nf)
        bp[nf] = *(const bf16x8*)
            &Psw[(nf * 16 + m) * 64 + (((c * 4 + quad) ^ (m & 7)) * 8)];
#pragma unroll
      for (int di = 0; di < 4; ++di) {
        bf16x8 av = *(const bf16x8*)
            &Vbase[(di * 16 + m) * 64 + ((c * 4 + quad) ^ (m & 7)) * 8];
        o[0][di] = mfma16(av, bp[0], o[0][di]);
        o[1][di] = mfma16(av, bp[1], o[1][di]);
      }
    }

    __syncthreads();
    buf ^= 1;
  }

#pragma unroll
  for (int nf = 0; nf < 2; ++nf) {
    float rl = 1.f / lrow[nf];
    int l = qt * 256 + wave * 32 + nf * 16 + m;
    bf16* hp = hout + (size_t)(b * NL + l) * NC + h * 64;
#pragma unroll
    for (int di = 0; di < 4; ++di) {
      bf16 pk[4];
#pragma unroll
      for (int r = 0; r < 4; ++r) pk[r] = __float2bfloat16(o[nf][di][r] * rl);
      *(uint2*)&hp[di * 16 + quad * 4] = *(const uint2*)pk;
    }
  }
}

extern "C" void kernel_launch(void* const* d_in, const int* in_sizes, int n_in,
                              void* d_out, int out_size, void* d_ws, size_t ws_size,
                              hipStream_t stream) {
  const float* x = (const float*)d_in[0];
  const float* gn_scale = (const float*)d_in[1];
  const float* gn_bias = (const float*)d_in[2];
  const float* qkv_w = (const float*)d_in[3];
  const float* qkv_b = (const float*)d_in[4];
  const float* proj_w = (const float*)d_in[5];
  const float* proj_b = (const float*)d_in[6];
  float* out = (float*)d_out;

  bf16* xn = (bf16*)d_out;  // aliases d_out first half; dead before GEMM1

  char* ws = (char*)d_ws;
  float2* part = (float2*)ws;               // 4096 B
  bf16* Qb = (bf16*)(ws + 4096);
  bf16* Kbuf = Qb + 4194304;
  bf16* Vt = Kbuf + 4194304;
  bf16* hat = Vt + 4194304;
  bf16* wqkvT = hat;   // aliased: dead before attn writes hat
  bf16* projT = Qb;    // aliased: written after attn, Q dead

  prep_kernel<<<3584, 256, 0, stream>>>(x, part, qkv_w, wqkvT);
  gn_apply_kernel<<<2048, 256, 0, stream>>>(x, part, gn_scale, gn_bias, xn);
  gemm_kernel<0, 128><<<dim3(24, 32), 256, 0, stream>>>(
      xn, wqkvT, qkv_b, nullptr, Qb, Kbuf, Vt, nullptr, 4096, 3072, 1024);
  attn_kernel<<<dim3(8, 16), 512, 0, stream>>>(Qb, Kbuf, Vt, hat, 0);
  attn_kernel<<<dim3(8, 16), 512, 0, stream>>>(Qb, Kbuf, Vt, hat, 16);
  transpose_f32_bf16<<<dim3(32, 32), dim3(32, 8), 0, stream>>>(proj_w, projT, 1024, 1024);
  gemm_kernel<1, 64><<<dim3(16, 32), 256, 0, stream>>>(
      hat, projT, proj_b, x, nullptr, nullptr, nullptr, out, 4096, 1024, 1024);
}

// Round 17
// 217.702 us; speedup vs baseline: 1.3148x; 1.3148x over previous
//
#include <hip/hip_runtime.h>
#include <hip/hip_bf16.h>

typedef __hip_bfloat16 bf16;
typedef __attribute__((ext_vector_type(8))) __bf16 bf16x8;
typedef __attribute__((ext_vector_type(4))) float floatx4;

#define NB 2
#define NL 2048
#define NC 1024
#define NH 16
#define ND 64

__device__ __forceinline__ void async_copy16(void* lds, const void* g) {
  __builtin_amdgcn_global_load_lds(
      (__attribute__((address_space(1))) void*)(const_cast<void*>(g)),
      (__attribute__((address_space(3))) void*)(lds), 16, 0, 0);
}

__device__ __forceinline__ floatx4 mfma16(bf16x8 a, bf16x8 b, floatx4 c) {
  return __builtin_amdgcn_mfma_f32_16x16x32_bf16(a, b, c, 0, 0, 0);
}

// ---------------- prep: gn partial stats (512 blocks) + qkv_w transpose -----
__global__ __launch_bounds__(256) void prep_kernel(
    const float* __restrict__ x, float2* __restrict__ part,
    const float* __restrict__ qkv_w, bf16* __restrict__ wqkvT) {
  __shared__ float t[32][33];
  __shared__ float rs[4], rss[4];
  int tid = threadIdx.x;
  if (blockIdx.x < 512) {
    int bg = blockIdx.x >> 3, sl = blockIdx.x & 7;
    int b = bg >> 5, g = bg & 31;
    const float* base = x + (size_t)b * NL * NC + (size_t)(sl * 256) * NC + g * 32;
    float s = 0.f, ss = 0.f;
    for (int vi = tid; vi < 2048; vi += 256) {
      int l = vi >> 3, j = (vi & 7) * 4;
      float4 u = *(const float4*)(base + (size_t)l * NC + j);
      s += u.x + u.y + u.z + u.w;
      ss += u.x * u.x + u.y * u.y + u.z * u.z + u.w * u.w;
    }
    for (int off = 32; off; off >>= 1) {
      s += __shfl_down(s, off);
      ss += __shfl_down(ss, off);
    }
    int wave = tid >> 6, lane = tid & 63;
    if (lane == 0) { rs[wave] = s; rss[wave] = ss; }
    __syncthreads();
    if (tid == 0) {
      part[blockIdx.x] = make_float2(rs[0] + rs[1] + rs[2] + rs[3],
                                     rss[0] + rss[1] + rss[2] + rss[3]);
    }
  } else {
    int tb = blockIdx.x - 512;
    int bx = tb % 96, by = tb / 96;
    int tx = tid & 31, ty = tid >> 5;
    int c0 = bx * 32, r0 = by * 32;
#pragma unroll
    for (int j = 0; j < 4; ++j)
      t[ty + j * 8][tx] = qkv_w[(size_t)(r0 + ty + j * 8) * 3072 + c0 + tx];
    __syncthreads();
#pragma unroll
    for (int j = 0; j < 4; ++j)
      wqkvT[(size_t)(c0 + ty + j * 8) * 1024 + r0 + tx] =
          __float2bfloat16(t[tx][ty + j * 8]);
  }
}

// ---------------- GroupNorm apply (folds partial reduction) -----------------
__global__ __launch_bounds__(256) void gn_apply_kernel(
    const float* __restrict__ x, const float2* __restrict__ part,
    const float* __restrict__ scale, const float* __restrict__ bias,
    bf16* __restrict__ xn) {
  size_t idx = (size_t)blockIdx.x * 256 + threadIdx.x;
  size_t e = idx * 8;
  int c = (int)(e & (NC - 1));
  int b = (int)(e >> 21);
  int bg = b * 32 + (c >> 5);
  float s = 0.f, ss = 0.f;
#pragma unroll
  for (int i = 0; i < 8; ++i) {
    float2 p = part[bg * 8 + i];
    s += p.x; ss += p.y;
  }
  float mean = s * (1.f / 65536.f);
  float var = ss * (1.f / 65536.f) - mean * mean;
  float rstd = rsqrtf(var + 1e-6f);
  float4 x0 = *(const float4*)(x + e);
  float4 x1 = *(const float4*)(x + e + 4);
  float4 s0 = *(const float4*)(scale + c);
  float4 s1 = *(const float4*)(scale + c + 4);
  float4 b0 = *(const float4*)(bias + c);
  float4 b1 = *(const float4*)(bias + c + 4);
  float xv[8] = {x0.x, x0.y, x0.z, x0.w, x1.x, x1.y, x1.z, x1.w};
  float sv[8] = {s0.x, s0.y, s0.z, s0.w, s1.x, s1.y, s1.z, s1.w};
  float bv[8] = {b0.x, b0.y, b0.z, b0.w, b1.x, b1.y, b1.z, b1.w};
  bf16 o[8];
#pragma unroll
  for (int k = 0; k < 8; ++k)
    o[k] = __float2bfloat16((xv[k] - mean) * rstd * sv[k] + bv[k]);
  *(uint4*)(xn + e) = *(const uint4*)o;
}

// ---------------- transpose + convert: fp32 [R,C] -> bf16 [C,R] -------------
__global__ void transpose_f32_bf16(const float* __restrict__ in,
                                   bf16* __restrict__ out, int R, int C) {
  __shared__ float t[32][33];
  int c0 = blockIdx.x * 32, r0 = blockIdx.y * 32;
#pragma unroll
  for (int j = 0; j < 4; ++j)
    t[threadIdx.y + j * 8][threadIdx.x] =
        in[(size_t)(r0 + threadIdx.y + j * 8) * C + c0 + threadIdx.x];
  __syncthreads();
#pragma unroll
  for (int j = 0; j < 4; ++j)
    out[(size_t)(c0 + threadIdx.y + j * 8) * R + r0 + threadIdx.x] =
        __float2bfloat16(t[threadIdx.x][threadIdx.y + j * 8]);
}

// ---------------- GEMM: two K-tiles per barrier epoch (BK=64) ---------------
// Dual 8KB stage buffers halve barrier/drain events (32 epochs for K=1024);
// 32 MFMA per epoch. LDS 32KB (NT=128) -> occupancy still VGPR-limited.
// MODE 0: scatter Q*(0.125*log2e), K, Vt (packed uint2 V stores)
// MODE 1: out_f32 = (xres + C) / sqrt(2)
template <int MODE, int NT>
__global__ __launch_bounds__(256) void gemm_kernel(
    const bf16* __restrict__ A, const bf16* __restrict__ Bt,
    const float* __restrict__ biasv, const float* __restrict__ xres,
    bf16* __restrict__ Qo, bf16* __restrict__ Ko, bf16* __restrict__ Vto,
    float* __restrict__ out, int M, int N, int K) {
  constexpr int NFR = NT / 32;
  __shared__ bf16 As[2][128 * 32];
  __shared__ bf16 Bs[2][NT * 32];
  int tid = threadIdx.x, wave = tid >> 6, lane = tid & 63;
  int col = lane & 15, quad = lane >> 4;
  int mB = blockIdx.y * 128, nB = blockIdx.x * NT;
  int wm = (wave >> 1) * 64, wn = (wave & 1) * (NT / 2);
  floatx4 acc[4][NFR];
#pragma unroll
  for (int i = 0; i < 4; ++i)
#pragma unroll
    for (int j = 0; j < NFR; ++j) acc[i][j] = (floatx4){0.f, 0.f, 0.f, 0.f};

  int rowOff = wave * 32 + (lane >> 2);
  int rowOffB = (NT == 128) ? rowOff : (wave * 16 + (lane >> 2));
  int kOff = (lane & 3) * 8;

  for (int k0 = 0; k0 < K; k0 += 64) {
    __syncthreads();
#pragma unroll
    for (int u = 0; u < 2; ++u) {
      int kk = k0 + u * 32;
      const bf16* ga = A + (size_t)(mB + rowOff) * K + kk + kOff;
      async_copy16(&As[u][(wave * 32) * 32], ga);
      async_copy16(&As[u][(wave * 32 + 16) * 32], ga + (size_t)16 * K);
      const bf16* gb = Bt + (size_t)(nB + rowOffB) * K + kk + kOff;
      if (NT == 128) {
        async_copy16(&Bs[u][(wave * 32) * 32], gb);
        async_copy16(&Bs[u][(wave * 32 + 16) * 32], gb + (size_t)16 * K);
      } else {
        async_copy16(&Bs[u][(wave * 16) * 32], gb);
      }
    }
    __syncthreads();
#pragma unroll
    for (int u = 0; u < 2; ++u) {
      bf16x8 af[4], bfr[NFR];
#pragma unroll
      for (int mi = 0; mi < 4; ++mi)
        af[mi] = *(const bf16x8*)&As[u][(wm + mi * 16 + col) * 32 + quad * 8];
#pragma unroll
      for (int ni = 0; ni < NFR; ++ni)
        bfr[ni] = *(const bf16x8*)&Bs[u][(wn + ni * 16 + col) * 32 + quad * 8];
#pragma unroll
      for (int mi = 0; mi < 4; ++mi)
#pragma unroll
        for (int ni = 0; ni < NFR; ++ni)
          acc[mi][ni] = mfma16(af[mi], bfr[ni], acc[mi][ni]);
    }
  }

#pragma unroll
  for (int mi = 0; mi < 4; ++mi)
#pragma unroll
    for (int ni = 0; ni < NFR; ++ni) {
      int row0 = mB + wm + mi * 16 + quad * 4;
      int ncol = nB + wn + ni * 16 + col;
      float vv[4];
#pragma unroll
      for (int r = 0; r < 4; ++r) vv[r] = acc[mi][ni][r] + biasv[ncol];
      if (MODE == 0) {
        int b = row0 >> 11, f0 = row0 & 2047;
        int h = ncol / 192, rr = ncol - h * 192;
        size_t bh = (size_t)(b * NH + h);
        if (rr < 64) {
#pragma unroll
          for (int r = 0; r < 4; ++r)
            Qo[(bh * NL + f0 + r) * 64 + rr] =
                __float2bfloat16(vv[r] * 0.18033688011112042f);  // 0.125*log2e
        } else if (rr < 128) {
#pragma unroll
          for (int r = 0; r < 4; ++r)
            Ko[(bh * NL + f0 + r) * 64 + rr - 64] = __float2bfloat16(vv[r]);
        } else {
          bf16 pk[4];
#pragma unroll
          for (int r = 0; r < 4; ++r) pk[r] = __float2bfloat16(vv[r]);
          *(uint2*)&Vto[(bh * 64 + (rr - 128)) * NL + f0] = *(const uint2*)pk;
        }
      } else {
#pragma unroll
        for (int r = 0; r < 4; ++r) {
          size_t o = (size_t)(row0 + r) * N + ncol;
          out[o] = (xres[o] + vv[r]) * 0.70710678118654752f;
        }
      }
    }
}

// ---------------- Flash attention v10 + exp2f (the 62.4us config) -----------
// 8 waves x 32 Q-rows = 256 rows/block; grid (8,32) = 256 blocks; double-
// buffered global_load_lds; XOR-chunk swizzle; one barrier/iter.
__global__ __launch_bounds__(512, 2) void attn_kernel(
    const bf16* __restrict__ Q, const bf16* __restrict__ Kb,
    const bf16* __restrict__ Vt, bf16* __restrict__ hout) {
  int qt = blockIdx.x, bh = blockIdx.y;
  int b = bh >> 4, h = bh & 15;
  int tid = threadIdx.x, wave = tid >> 6, lane = tid & 63;
  int m = lane & 15, quad = lane >> 4;

  __shared__ bf16 Kd[2][4096];
  __shared__ bf16 Vd[2][4096];
  __shared__ bf16 Pp[8][2048];

  bf16* Psw = Pp[wave];

  const bf16* Kg = Kb + (size_t)bh * NL * 64;
  const bf16* Vg = Vt + (size_t)bh * 64 * NL;

  bf16x8 bq[2][2];
  {
    const bf16* Qg = Q + ((size_t)bh * NL + qt * 256 + wave * 32) * 64;
#pragma unroll
    for (int nf = 0; nf < 2; ++nf)
#pragma unroll
      for (int c = 0; c < 2; ++c)
        bq[nf][c] = *(const bf16x8*)&Qg[(size_t)(nf * 16 + m) * 64 + c * 32 + quad * 8];
  }

  float lrow[2] = {0.f, 0.f};
  floatx4 o[2][4];
#pragma unroll
  for (int nf = 0; nf < 2; ++nf)
#pragma unroll
    for (int di = 0; di < 4; ++di) o[nf][di] = (floatx4){0.f, 0.f, 0.f, 0.f};

  int srow = lane >> 3, schunk = lane & 7;

  auto stage = [&](int bufi, int t0) {
    int r0 = wave * 8;
    int r = r0 + srow;
    int cg = schunk ^ (r & 7);
    async_copy16(&Kd[bufi][r0 * 64], Kg + (size_t)(t0 + r) * 64 + cg * 8);
    async_copy16(&Vd[bufi][r0 * 64], Vg + (size_t)r * NL + t0 + cg * 8);
  };

  stage(0, 0);
  __syncthreads();

  int buf = 0;
  for (int t0 = 0; t0 < NL; t0 += 64) {
    if (t0 + 64 < NL) stage(buf ^ 1, t0 + 64);

    const bf16* Kbase = Kd[buf];
    const bf16* Vbase = Vd[buf];

    floatx4 s[2][4];
#pragma unroll
    for (int nf = 0; nf < 2; ++nf)
#pragma unroll
      for (int ti = 0; ti < 4; ++ti) s[nf][ti] = (floatx4){0.f, 0.f, 0.f, 0.f};
#pragma unroll
    for (int ti = 0; ti < 4; ++ti)
#pragma unroll
      for (int c = 0; c < 2; ++c) {
        bf16x8 ak = *(const bf16x8*)
            &Kbase[(ti * 16 + m) * 64 + ((c * 4 + quad) ^ (m & 7)) * 8];
        s[0][ti] = mfma16(ak, bq[0][c], s[0][ti]);
        s[1][ti] = mfma16(ak, bq[1][c], s[1][ti]);
      }

#pragma unroll
    for (int nf = 0; nf < 2; ++nf) {
      float ls = 0.f;
#pragma unroll
      for (int ti = 0; ti < 4; ++ti)
#pragma unroll
        for (int r = 0; r < 4; ++r) {
          float p = exp2f(s[nf][ti][r]);   // Q pre-scaled by 0.125*log2e
          s[nf][ti][r] = p;
          ls += p;
        }
      ls += __shfl_xor(ls, 16);
      ls += __shfl_xor(ls, 32);
      lrow[nf] += ls;
#pragma unroll
      for (int ti = 0; ti < 4; ++ti) {
        bf16 pk[4];
#pragma unroll
        for (int r = 0; r < 4; ++r) pk[r] = __float2bfloat16(s[nf][ti][r]);
        int ct = ti * 2 + (quad >> 1);
        *(uint2*)&Psw[(nf * 16 + m) * 64 + ((ct ^ (m & 7)) * 8) + (quad & 1) * 4] =
            *(const uint2*)pk;
      }
    }

#pragma unroll
    for (int c = 0; c < 2; ++c) {
      bf16x8 bp[2];
#pragma unroll
      for (int nf = 0; nf < 2; ++nf)
        bp[nf] = *(const bf16x8*)
            &Psw[(nf * 16 + m) * 64 + (((c * 4 + quad) ^ (m & 7)) * 8)];
#pragma unroll
      for (int di = 0; di < 4; ++di) {
        bf16x8 av = *(const bf16x8*)
            &Vbase[(di * 16 + m) * 64 + ((c * 4 + quad) ^ (m & 7)) * 8];
        o[0][di] = mfma16(av, bp[0], o[0][di]);
        o[1][di] = mfma16(av, bp[1], o[1][di]);
      }
    }

    __syncthreads();
    buf ^= 1;
  }

#pragma unroll
  for (int nf = 0; nf < 2; ++nf) {
    float rl = 1.f / lrow[nf];
    int l = qt * 256 + wave * 32 + nf * 16 + m;
    bf16* hp = hout + (size_t)(b * NL + l) * NC + h * 64;
#pragma unroll
    for (int di = 0; di < 4; ++di) {
      bf16 pk[4];
#pragma unroll
      for (int r = 0; r < 4; ++r) pk[r] = __float2bfloat16(o[nf][di][r] * rl);
      *(uint2*)&hp[di * 16 + quad * 4] = *(const uint2*)pk;
    }
  }
}

extern "C" void kernel_launch(void* const* d_in, const int* in_sizes, int n_in,
                              void* d_out, int out_size, void* d_ws, size_t ws_size,
                              hipStream_t stream) {
  const float* x = (const float*)d_in[0];
  const float* gn_scale = (const float*)d_in[1];
  const float* gn_bias = (const float*)d_in[2];
  const float* qkv_w = (const float*)d_in[3];
  const float* qkv_b = (const float*)d_in[4];
  const float* proj_w = (const float*)d_in[5];
  const float* proj_b = (const float*)d_in[6];
  float* out = (float*)d_out;

  bf16* xn = (bf16*)d_out;  // aliases d_out first half; dead before GEMM1

  char* ws = (char*)d_ws;
  float2* part = (float2*)ws;               // 4096 B
  bf16* Qb = (bf16*)(ws + 4096);
  bf16* Kbuf = Qb + 4194304;
  bf16* Vt = Kbuf + 4194304;
  bf16* hat = Vt + 4194304;
  bf16* wqkvT = hat;   // aliased: dead before attn writes hat
  bf16* projT = Qb;    // aliased: written after attn, Q dead

  prep_kernel<<<3584, 256, 0, stream>>>(x, part, qkv_w, wqkvT);
  gn_apply_kernel<<<2048, 256, 0, stream>>>(x, part, gn_scale, gn_bias, xn);
  gemm_kernel<0, 128><<<dim3(24, 32), 256, 0, stream>>>(
      xn, wqkvT, qkv_b, nullptr, Qb, Kbuf, Vt, nullptr, 4096, 3072, 1024);
  attn_kernel<<<dim3(8, 32), 512, 0, stream>>>(Qb, Kbuf, Vt, hat);
  transpose_f32_bf16<<<dim3(32, 32), dim3(32, 8), 0, stream>>>(proj_w, projT, 1024, 1024);
  gemm_kernel<1, 64><<<dim3(16, 32), 256, 0, stream>>>(
      hat, projT, proj_b, x, nullptr, nullptr, nullptr, out, 4096, 1024, 1024);
}

// Round 18
// 201.006 us; speedup vs baseline: 1.4240x; 1.0831x over previous
//
#include <hip/hip_runtime.h>
#include <hip/hip_bf16.h>

typedef __hip_bfloat16 bf16;
typedef __attribute__((ext_vector_type(8))) __bf16 bf16x8;
typedef __attribute__((ext_vector_type(4))) float floatx4;

#define NB 2
#define NL 2048
#define NC 1024
#define NH 16
#define ND 64

__device__ __forceinline__ void async_copy16(void* lds, const void* g) {
  __builtin_amdgcn_global_load_lds(
      (__attribute__((address_space(1))) void*)(const_cast<void*>(g)),
      (__attribute__((address_space(3))) void*)(lds), 16, 0, 0);
}

__device__ __forceinline__ floatx4 mfma16(bf16x8 a, bf16x8 b, floatx4 c) {
  return __builtin_amdgcn_mfma_f32_16x16x32_bf16(a, b, c, 0, 0, 0);
}

// raw v_exp_f32: input in log2 domain (Q pre-scaled by 0.125*log2e in gemm0)
__device__ __forceinline__ float fast_exp2(float x) {
  return __builtin_amdgcn_exp2f(x);
}

// ---------------- prep: gn partial stats (512 blocks) + qkv_w transpose -----
__global__ __launch_bounds__(256) void prep_kernel(
    const float* __restrict__ x, float2* __restrict__ part,
    const float* __restrict__ qkv_w, bf16* __restrict__ wqkvT) {
  __shared__ float t[32][33];
  __shared__ float rs[4], rss[4];
  int tid = threadIdx.x;
  if (blockIdx.x < 512) {
    int bg = blockIdx.x >> 3, sl = blockIdx.x & 7;
    int b = bg >> 5, g = bg & 31;
    const float* base = x + (size_t)b * NL * NC + (size_t)(sl * 256) * NC + g * 32;
    float s = 0.f, ss = 0.f;
    for (int vi = tid; vi < 2048; vi += 256) {
      int l = vi >> 3, j = (vi & 7) * 4;
      float4 u = *(const float4*)(base + (size_t)l * NC + j);
      s += u.x + u.y + u.z + u.w;
      ss += u.x * u.x + u.y * u.y + u.z * u.z + u.w * u.w;
    }
    for (int off = 32; off; off >>= 1) {
      s += __shfl_down(s, off);
      ss += __shfl_down(ss, off);
    }
    int wave = tid >> 6, lane = tid & 63;
    if (lane == 0) { rs[wave] = s; rss[wave] = ss; }
    __syncthreads();
    if (tid == 0) {
      part[blockIdx.x] = make_float2(rs[0] + rs[1] + rs[2] + rs[3],
                                     rss[0] + rss[1] + rss[2] + rss[3]);
    }
  } else {
    int tb = blockIdx.x - 512;
    int bx = tb % 96, by = tb / 96;
    int tx = tid & 31, ty = tid >> 5;
    int c0 = bx * 32, r0 = by * 32;
#pragma unroll
    for (int j = 0; j < 4; ++j)
      t[ty + j * 8][tx] = qkv_w[(size_t)(r0 + ty + j * 8) * 3072 + c0 + tx];
    __syncthreads();
#pragma unroll
    for (int j = 0; j < 4; ++j)
      wqkvT[(size_t)(c0 + ty + j * 8) * 1024 + r0 + tx] =
          __float2bfloat16(t[tx][ty + j * 8]);
  }
}

// ---------------- GroupNorm apply (folds partial reduction) -----------------
__global__ __launch_bounds__(256) void gn_apply_kernel(
    const float* __restrict__ x, const float2* __restrict__ part,
    const float* __restrict__ scale, const float* __restrict__ bias,
    bf16* __restrict__ xn) {
  size_t idx = (size_t)blockIdx.x * 256 + threadIdx.x;
  size_t e = idx * 8;
  int c = (int)(e & (NC - 1));
  int b = (int)(e >> 21);
  int bg = b * 32 + (c >> 5);
  float s = 0.f, ss = 0.f;
#pragma unroll
  for (int i = 0; i < 8; ++i) {
    float2 p = part[bg * 8 + i];
    s += p.x; ss += p.y;
  }
  float mean = s * (1.f / 65536.f);
  float var = ss * (1.f / 65536.f) - mean * mean;
  float rstd = rsqrtf(var + 1e-6f);
  float4 x0 = *(const float4*)(x + e);
  float4 x1 = *(const float4*)(x + e + 4);
  float4 s0 = *(const float4*)(scale + c);
  float4 s1 = *(const float4*)(scale + c + 4);
  float4 b0 = *(const float4*)(bias + c);
  float4 b1 = *(const float4*)(bias + c + 4);
  float xv[8] = {x0.x, x0.y, x0.z, x0.w, x1.x, x1.y, x1.z, x1.w};
  float sv[8] = {s0.x, s0.y, s0.z, s0.w, s1.x, s1.y, s1.z, s1.w};
  float bv[8] = {b0.x, b0.y, b0.z, b0.w, b1.x, b1.y, b1.z, b1.w};
  bf16 o[8];
#pragma unroll
  for (int k = 0; k < 8; ++k)
    o[k] = __float2bfloat16((xv[k] - mean) * rstd * sv[k] + bv[k]);
  *(uint4*)(xn + e) = *(const uint4*)o;
}

// ---------------- transpose + convert: fp32 [R,C] -> bf16 [C,R] -------------
__global__ void transpose_f32_bf16(const float* __restrict__ in,
                                   bf16* __restrict__ out, int R, int C) {
  __shared__ float t[32][33];
  int c0 = blockIdx.x * 32, r0 = blockIdx.y * 32;
#pragma unroll
  for (int j = 0; j < 4; ++j)
    t[threadIdx.y + j * 8][threadIdx.x] =
        in[(size_t)(r0 + threadIdx.y + j * 8) * C + c0 + threadIdx.x];
  __syncthreads();
#pragma unroll
  for (int j = 0; j < 4; ++j)
    out[(size_t)(c0 + threadIdx.y + j * 8) * R + r0 + threadIdx.x] =
        __float2bfloat16(t[threadIdx.x][threadIdx.y + j * 8]);
}

// ---------------- GEMM: two K-tiles per barrier epoch (BK=64) ---------------
// MODE 0: scatter Q*(0.125*log2e), K, Vt (packed uint2 V stores)
// MODE 1: out_f32 = (xres + C) / sqrt(2)
template <int MODE, int NT>
__global__ __launch_bounds__(256) void gemm_kernel(
    const bf16* __restrict__ A, const bf16* __restrict__ Bt,
    const float* __restrict__ biasv, const float* __restrict__ xres,
    bf16* __restrict__ Qo, bf16* __restrict__ Ko, bf16* __restrict__ Vto,
    float* __restrict__ out, int M, int N, int K) {
  constexpr int NFR = NT / 32;
  __shared__ bf16 As[2][128 * 32];
  __shared__ bf16 Bs[2][NT * 32];
  int tid = threadIdx.x, wave = tid >> 6, lane = tid & 63;
  int col = lane & 15, quad = lane >> 4;
  int mB = blockIdx.y * 128, nB = blockIdx.x * NT;
  int wm = (wave >> 1) * 64, wn = (wave & 1) * (NT / 2);
  floatx4 acc[4][NFR];
#pragma unroll
  for (int i = 0; i < 4; ++i)
#pragma unroll
    for (int j = 0; j < NFR; ++j) acc[i][j] = (floatx4){0.f, 0.f, 0.f, 0.f};

  int rowOff = wave * 32 + (lane >> 2);
  int rowOffB = (NT == 128) ? rowOff : (wave * 16 + (lane >> 2));
  int kOff = (lane & 3) * 8;

  for (int k0 = 0; k0 < K; k0 += 64) {
    __syncthreads();
#pragma unroll
    for (int u = 0; u < 2; ++u) {
      int kk = k0 + u * 32;
      const bf16* ga = A + (size_t)(mB + rowOff) * K + kk + kOff;
      async_copy16(&As[u][(wave * 32) * 32], ga);
      async_copy16(&As[u][(wave * 32 + 16) * 32], ga + (size_t)16 * K);
      const bf16* gb = Bt + (size_t)(nB + rowOffB) * K + kk + kOff;
      if (NT == 128) {
        async_copy16(&Bs[u][(wave * 32) * 32], gb);
        async_copy16(&Bs[u][(wave * 32 + 16) * 32], gb + (size_t)16 * K);
      } else {
        async_copy16(&Bs[u][(wave * 16) * 32], gb);
      }
    }
    __syncthreads();
#pragma unroll
    for (int u = 0; u < 2; ++u) {
      bf16x8 af[4], bfr[NFR];
#pragma unroll
      for (int mi = 0; mi < 4; ++mi)
        af[mi] = *(const bf16x8*)&As[u][(wm + mi * 16 + col) * 32 + quad * 8];
#pragma unroll
      for (int ni = 0; ni < NFR; ++ni)
        bfr[ni] = *(const bf16x8*)&Bs[u][(wn + ni * 16 + col) * 32 + quad * 8];
#pragma unroll
      for (int mi = 0; mi < 4; ++mi)
#pragma unroll
        for (int ni = 0; ni < NFR; ++ni)
          acc[mi][ni] = mfma16(af[mi], bfr[ni], acc[mi][ni]);
    }
  }

#pragma unroll
  for (int mi = 0; mi < 4; ++mi)
#pragma unroll
    for (int ni = 0; ni < NFR; ++ni) {
      int row0 = mB + wm + mi * 16 + quad * 4;
      int ncol = nB + wn + ni * 16 + col;
      float vv[4];
#pragma unroll
      for (int r = 0; r < 4; ++r) vv[r] = acc[mi][ni][r] + biasv[ncol];
      if (MODE == 0) {
        int b = row0 >> 11, f0 = row0 & 2047;
        int h = ncol / 192, rr = ncol - h * 192;
        size_t bh = (size_t)(b * NH + h);
        if (rr < 64) {
#pragma unroll
          for (int r = 0; r < 4; ++r)
            Qo[(bh * NL + f0 + r) * 64 + rr] =
                __float2bfloat16(vv[r] * 0.18033688011112042f);  // 0.125*log2e
        } else if (rr < 128) {
#pragma unroll
          for (int r = 0; r < 4; ++r)
            Ko[(bh * NL + f0 + r) * 64 + rr - 64] = __float2bfloat16(vv[r]);
        } else {
          bf16 pk[4];
#pragma unroll
          for (int r = 0; r < 4; ++r) pk[r] = __float2bfloat16(vv[r]);
          *(uint2*)&Vto[(bh * 64 + (rr - 128)) * NL + f0] = *(const uint2*)pk;
        }
      } else {
#pragma unroll
        for (int r = 0; r < 4; ++r) {
          size_t o = (size_t)(row0 + r) * N + ncol;
          out[o] = (xres[o] + vv[r]) * 0.70710678118654752f;
        }
      }
    }
}

// ---------------- Flash attention v10 + raw v_exp_f32 -----------------------
// 8 waves x 32 Q-rows = 256 rows/block; grid (8,32) = 256 blocks; double-
// buffered global_load_lds; XOR-chunk swizzle; one barrier/iter.
// exp via __builtin_amdgcn_exp2f (1 instr; libm exp2f was a +10% VALU trap).
__global__ __launch_bounds__(512, 2) void attn_kernel(
    const bf16* __restrict__ Q, const bf16* __restrict__ Kb,
    const bf16* __restrict__ Vt, bf16* __restrict__ hout) {
  int qt = blockIdx.x, bh = blockIdx.y;
  int b = bh >> 4, h = bh & 15;
  int tid = threadIdx.x, wave = tid >> 6, lane = tid & 63;
  int m = lane & 15, quad = lane >> 4;

  __shared__ bf16 Kd[2][4096];
  __shared__ bf16 Vd[2][4096];
  __shared__ bf16 Pp[8][2048];

  bf16* Psw = Pp[wave];

  const bf16* Kg = Kb + (size_t)bh * NL * 64;
  const bf16* Vg = Vt + (size_t)bh * 64 * NL;

  bf16x8 bq[2][2];
  {
    const bf16* Qg = Q + ((size_t)bh * NL + qt * 256 + wave * 32) * 64;
#pragma unroll
    for (int nf = 0; nf < 2; ++nf)
#pragma unroll
      for (int c = 0; c < 2; ++c)
        bq[nf][c] = *(const bf16x8*)&Qg[(size_t)(nf * 16 + m) * 64 + c * 32 + quad * 8];
  }

  float lrow[2] = {0.f, 0.f};
  floatx4 o[2][4];
#pragma unroll
  for (int nf = 0; nf < 2; ++nf)
#pragma unroll
    for (int di = 0; di < 4; ++di) o[nf][di] = (floatx4){0.f, 0.f, 0.f, 0.f};

  int srow = lane >> 3, schunk = lane & 7;

  auto stage = [&](int bufi, int t0) {
    int r0 = wave * 8;
    int r = r0 + srow;
    int cg = schunk ^ (r & 7);
    async_copy16(&Kd[bufi][r0 * 64], Kg + (size_t)(t0 + r) * 64 + cg * 8);
    async_copy16(&Vd[bufi][r0 * 64], Vg + (size_t)r * NL + t0 + cg * 8);
  };

  stage(0, 0);
  __syncthreads();

  int buf = 0;
  for (int t0 = 0; t0 < NL; t0 += 64) {
    if (t0 + 64 < NL) stage(buf ^ 1, t0 + 64);

    const bf16* Kbase = Kd[buf];
    const bf16* Vbase = Vd[buf];

    floatx4 s[2][4];
#pragma unroll
    for (int nf = 0; nf < 2; ++nf)
#pragma unroll
      for (int ti = 0; ti < 4; ++ti) s[nf][ti] = (floatx4){0.f, 0.f, 0.f, 0.f};
#pragma unroll
    for (int ti = 0; ti < 4; ++ti)
#pragma unroll
      for (int c = 0; c < 2; ++c) {
        bf16x8 ak = *(const bf16x8*)
            &Kbase[(ti * 16 + m) * 64 + ((c * 4 + quad) ^ (m & 7)) * 8];
        s[0][ti] = mfma16(ak, bq[0][c], s[0][ti]);
        s[1][ti] = mfma16(ak, bq[1][c], s[1][ti]);
      }

#pragma unroll
    for (int nf = 0; nf < 2; ++nf) {
      float ls = 0.f;
#pragma unroll
      for (int ti = 0; ti < 4; ++ti)
#pragma unroll
        for (int r = 0; r < 4; ++r) {
          float p = fast_exp2(s[nf][ti][r]);  // Q pre-scaled by 0.125*log2e
          s[nf][ti][r] = p;
          ls += p;
        }
      ls += __shfl_xor(ls, 16);
      ls += __shfl_xor(ls, 32);
      lrow[nf] += ls;
#pragma unroll
      for (int ti = 0; ti < 4; ++ti) {
        bf16 pk[4];
#pragma unroll
        for (int r = 0; r < 4; ++r) pk[r] = __float2bfloat16(s[nf][ti][r]);
        int ct = ti * 2 + (quad >> 1);
        *(uint2*)&Psw[(nf * 16 + m) * 64 + ((ct ^ (m & 7)) * 8) + (quad & 1) * 4] =
            *(const uint2*)pk;
      }
    }

#pragma unroll
    for (int c = 0; c < 2; ++c) {
      bf16x8 bp[2];
#pragma unroll
      for (int nf = 0; nf < 2; ++nf)
        bp[nf] = *(const bf16x8*)
            &Psw[(nf * 16 + m) * 64 + (((c * 4 + quad) ^ (m & 7)) * 8)];
#pragma unroll
      for (int di = 0; di < 4; ++di) {
        bf16x8 av = *(const bf16x8*)
            &Vbase[(di * 16 + m) * 64 + ((c * 4 + quad) ^ (m & 7)) * 8];
        o[0][di] = mfma16(av, bp[0], o[0][di]);
        o[1][di] = mfma16(av, bp[1], o[1][di]);
      }
    }

    __syncthreads();
    buf ^= 1;
  }

#pragma unroll
  for (int nf = 0; nf < 2; ++nf) {
    float rl = 1.f / lrow[nf];
    int l = qt * 256 + wave * 32 + nf * 16 + m;
    bf16* hp = hout + (size_t)(b * NL + l) * NC + h * 64;
#pragma unroll
    for (int di = 0; di < 4; ++di) {
      bf16 pk[4];
#pragma unroll
      for (int r = 0; r < 4; ++r) pk[r] = __float2bfloat16(o[nf][di][r] * rl);
      *(uint2*)&hp[di * 16 + quad * 4] = *(const uint2*)pk;
    }
  }
}

extern "C" void kernel_launch(void* const* d_in, const int* in_sizes, int n_in,
                              void* d_out, int out_size, void* d_ws, size_t ws_size,
                              hipStream_t stream) {
  const float* x = (const float*)d_in[0];
  const float* gn_scale = (const float*)d_in[1];
  const float* gn_bias = (const float*)d_in[2];
  const float* qkv_w = (const float*)d_in[3];
  const float* qkv_b = (const float*)d_in[4];
  const float* proj_w = (const float*)d_in[5];
  const float* proj_b = (const float*)d_in[6];
  float* out = (float*)d_out;

  bf16* xn = (bf16*)d_out;  // aliases d_out first half; dead before GEMM1

  char* ws = (char*)d_ws;
  float2* part = (float2*)ws;               // 4096 B
  bf16* Qb = (bf16*)(ws + 4096);
  bf16* Kbuf = Qb + 4194304;
  bf16* Vt = Kbuf + 4194304;
  bf16* hat = Vt + 4194304;
  bf16* wqkvT = hat;   // aliased: dead before attn writes hat
  bf16* projT = Qb;    // aliased: written after attn, Q dead

  prep_kernel<<<3584, 256, 0, stream>>>(x, part, qkv_w, wqkvT);
  gn_apply_kernel<<<2048, 256, 0, stream>>>(x, part, gn_scale, gn_bias, xn);
  gemm_kernel<0, 128><<<dim3(24, 32), 256, 0, stream>>>(
      xn, wqkvT, qkv_b, nullptr, Qb, Kbuf, Vt, nullptr, 4096, 3072, 1024);
  attn_kernel<<<dim3(8, 32), 512, 0, stream>>>(Qb, Kbuf, Vt, hat);
  transpose_f32_bf16<<<dim3(32, 32), dim3(32, 8), 0, stream>>>(proj_w, projT, 1024, 1024);
  gemm_kernel<1, 64><<<dim3(16, 32), 256, 0, stream>>>(
      hat, projT, proj_b, x, nullptr, nullptr, nullptr, out, 4096, 1024, 1024);
}